// Round 1
// baseline (189.744 us; speedup 1.0000x reference)
//
#include <hip/hip_runtime.h>

namespace {
constexpr int KS   = 5;    // reassembly kernel
constexpr int UWF  = 3;    // upsample factor (width)
constexpr int HID_ = 64;
constexpr int BB   = 4, HH = 512, WW_ = 512;
constexpr int HW   = HH * WW_;
constexpr int OW   = WW_ * UWF;          // 1536
constexpr int OPL  = HH * OW;            // out plane 786432
}

__global__ __launch_bounds__(256) void xg_mean_kernel(const float* __restrict__ x,
                                                      float* __restrict__ xg) {
    int idx = blockIdx.x * 256 + threadIdx.x;   // over B*H*W, grid exact
    int b  = idx >> 18;
    int hw = idx & (HW - 1);
    const float* xb = x + (size_t)b * 3 * HW;
    xg[idx] = (xb[hw] + xb[HW + hw] + xb[2 * HW + hw]) * (1.0f / 3.0f);
}

template <bool USE_WS>
__global__ __launch_bounds__(256) void carafe_fused_kernel(
    const float* __restrict__ x, const float* __restrict__ xg,
    const float* __restrict__ w1, const float* __restrict__ b1,
    const float* __restrict__ w2, const float* __restrict__ b2,
    const float* __restrict__ wp, const float* __restrict__ bp,
    float* __restrict__ out) {
  int idx = blockIdx.x * 256 + threadIdx.x;     // over B*H*W, grid exact
  int b  = idx >> 18;
  int hw = idx & (HW - 1);
  int h  = hw >> 9;
  int w  = hw & (WW_ - 1);

  // 5x5 xg window (zero-padded), covers both the 3x3 conv and the reassembly taps
  float xw[KS][KS];
#pragma unroll
  for (int dy = 0; dy < KS; ++dy) {
    int y = h + dy - 2;
    bool yok = ((unsigned)y < (unsigned)HH);
#pragma unroll
    for (int dx = 0; dx < KS; ++dx) {
      int xc = w + dx - 2;
      bool ok = yok && ((unsigned)xc < (unsigned)WW_);
      float v = 0.0f;
      if (ok) {
        if (USE_WS) {
          v = xg[(size_t)b * HW + y * WW_ + xc];
        } else {
          const float* xb = x + (size_t)b * 3 * HW + y * WW_ + xc;
          v = (xb[0] + xb[HW] + xb[2 * HW]) * (1.0f / 3.0f);
        }
      }
      xw[dy][dx] = v;
    }
  }

  // 3x3 conv (centered) + ReLU -> 64 hidden
  float hb[HID_];
#pragma unroll
  for (int c = 0; c < HID_; ++c) {
    float acc = b1[c];
#pragma unroll
    for (int ky = 0; ky < 3; ++ky)
#pragma unroll
      for (int kx = 0; kx < 3; ++kx)
        acc = fmaf(xw[1 + ky][1 + kx], w1[c * 9 + ky * 3 + kx], acc);
    hb[c] = fmaxf(acc, 0.0f);
  }

  // 1x1 conv -> 75 logits; streaming softmax (no max-sub: |logit| << 1) + reassembly
  float accv[UWF] = {0.f, 0.f, 0.f};
  float sumv[UWF] = {0.f, 0.f, 0.f};
#pragma unroll
  for (int kk = 0; kk < KS * KS; ++kk) {
    float nv = xw[kk / KS][kk % KS];
#pragma unroll
    for (int v = 0; v < UWF; ++v) {
      int ch = kk * UWF + v;   // ker channel = kk*UH*UW + u*UW + v, u==0
      float l = b2[ch];
      const float* wrow = w2 + (size_t)ch * HID_;
#pragma unroll
      for (int c = 0; c < HID_; ++c) l = fmaf(hb[c], wrow[c], l);
      float e = __expf(l);
      sumv[v] += e;
      accv[v] = fmaf(e, nv, accv[v]);
    }
  }

  float wps = wp[0], bps = bp[0];
#pragma unroll
  for (int v = 0; v < UWF; ++v) {
    float o = (accv[v] / sumv[v]) * wps + bps;
    size_t base = (size_t)h * OW + (size_t)w * UWF + v;
#pragma unroll
    for (int c = 0; c < 3; ++c) {
      out[(size_t)(b * 3 + c) * OPL + base] = o;
    }
  }
}

extern "C" void kernel_launch(void* const* d_in, const int* in_sizes, int n_in,
                              void* d_out, int out_size, void* d_ws, size_t ws_size,
                              hipStream_t stream) {
  const float* x  = (const float*)d_in[0];
  const float* w1 = (const float*)d_in[1];
  const float* b1 = (const float*)d_in[2];
  const float* w2 = (const float*)d_in[3];
  const float* b2 = (const float*)d_in[4];
  const float* wp = (const float*)d_in[5];
  const float* bp = (const float*)d_in[6];
  float* out = (float*)d_out;

  const int total  = BB * HW;              // 1,048,576
  const int block  = 256;
  const int grid   = total / block;        // 4096, exact

  const size_t xg_bytes = (size_t)total * sizeof(float);
  if (ws_size >= xg_bytes) {
    float* xg = (float*)d_ws;
    xg_mean_kernel<<<grid, block, 0, stream>>>(x, xg);
    carafe_fused_kernel<true><<<grid, block, 0, stream>>>(x, xg, w1, b1, w2, b2, wp, bp, out);
  } else {
    carafe_fused_kernel<false><<<grid, block, 0, stream>>>(x, nullptr, w1, b1, w2, b2, wp, bp, out);
  }
}